// Round 7
// baseline (159.492 us; speedup 1.0000x reference)
//
#include <hip/hip_runtime.h>
#include <hip/hip_bf16.h>
#include <math.h>

// Problem shape (fixed): x [B,T,D] fp32, log_alpha scalar fp32, out [B,T,D] fp32.
#define B_ 4
#define T_ 4096
#define D_ 512
#define TM 64                  // t rows per block (one wave)
#define TS 128                 // s cols per block
#define BK 32                  // K per pipeline step
#define STEPS (D_ / BK)        // 16
#define NPAIR 1056             // sum_{ti=0}^{63} (ti/2 + 1) causal tile pairs

// Workspace layout (needs 64 KiB + 16 MiB):
//   [0 .. 64KiB)                maxsim as order-preserving uint32 [B*T]
//   [64KiB .. 64KiB+B*T*D*2)    xn: normalized rows, bf16 bits (ushort)

typedef short bf16x8 __attribute__((ext_vector_type(8)));
typedef float f32x4 __attribute__((ext_vector_type(4)));

__device__ __forceinline__ unsigned short f2bf(float f) {
    unsigned u = __float_as_uint(f);
    u += 0x7FFFu + ((u >> 16) & 1u);   // RNE
    return (unsigned short)(u >> 16);
}
// monotone float -> uint so unsigned atomicMax orders like float
__device__ __forceinline__ unsigned f2ord(float f) {
    unsigned u = __float_as_uint(f);
    return (u & 0x80000000u) ? ~u : (u | 0x80000000u);
}
__device__ __forceinline__ float ord2f(unsigned u) {
    unsigned b = (u & 0x80000000u) ? (u ^ 0x80000000u) : ~u;
    return __uint_as_float(b);
}

__device__ __forceinline__ void async16(const unsigned short* g, unsigned short* l) {
    // 16B/lane global->LDS DMA; LDS dest = wave-uniform base + lane*16
    __builtin_amdgcn_global_load_lds(
        (const __attribute__((address_space(1))) unsigned int*)g,
        (__attribute__((address_space(3))) unsigned int*)l, 16, 0, 0);
}

// ---- Kernel 1: one wave per row. inv-norm + bf16 row write + maxsim init ----
__global__ __launch_bounds__(256) void k_norm(const float* __restrict__ x,
                                              unsigned short* __restrict__ xn,
                                              unsigned* __restrict__ maxsim) {
    int w = (blockIdx.x * 256 + threadIdx.x) >> 6;   // row id (B*T rows)
    int lane = threadIdx.x & 63;
    const float4* xr = (const float4*)(x + (size_t)w * D_);
    float4 a = xr[lane];          // lane-contiguous: full coalescing
    float4 b = xr[lane + 64];
    float ss = a.x * a.x + a.y * a.y + a.z * a.z + a.w * a.w +
               b.x * b.x + b.y * b.y + b.z * b.z + b.w * b.w;
#pragma unroll
    for (int off = 32; off > 0; off >>= 1) ss += __shfl_xor(ss, off);
    float inv = 1.0f / fmaxf(sqrtf(ss), 1e-12f);
    unsigned u0 = (unsigned)f2bf(a.x * inv) | ((unsigned)f2bf(a.y * inv) << 16);
    unsigned u1 = (unsigned)f2bf(a.z * inv) | ((unsigned)f2bf(a.w * inv) << 16);
    unsigned u2 = (unsigned)f2bf(b.x * inv) | ((unsigned)f2bf(b.y * inv) << 16);
    unsigned u3 = (unsigned)f2bf(b.z * inv) | ((unsigned)f2bf(b.w * inv) << 16);
    uint2* xo = (uint2*)(xn + (size_t)w * D_);
    xo[lane]      = make_uint2(u0, u1);
    xo[lane + 64] = make_uint2(u2, u3);
    if (lane == 0) maxsim[w] = f2ord(-2.0f);
}

// ---- Kernel 2: ONE WAVE per block, 64x128 tile, private LDS staging ----
// ZERO barriers: each wave DMA-stages its own A(64 rows)+B(128 rows) K-slabs
// into its own LDS; per-wave vmcnt is the only sync. 2-stage ping-pong,
// 12 DMAs/step; while step k computes, step k+1's DMAs are in flight
// (vmcnt(12) waits only on step-k's, issued a full step earlier).
// LDS layout per stage: A[64 rows][32 el] then B[128 rows][32 el], row
// stride 64 B = 4 chunks of 16 B. XOR swizzle: chunk c of row r stored at
// position c ^ (r&3) ^ ((r>>2)&3)  ->  reader's 16-lane groups hit each
// 4-bank group at most 2-way (free, m136).
// NOTE: history — (256,4) launch_bounds spilled (R2); BK=64 killed occupancy
// (R3); direct-from-global fragments are TA-bound (R5); per-step barriers
// re-correlate waves (R1/R6). This design removes the barrier entirely.
__global__ __launch_bounds__(64) void k_maxsim(const unsigned short* __restrict__ xn,
                                               unsigned* __restrict__ maxsim) {
    __shared__ __align__(16) unsigned short Buf[2][6144];  // stage: A[0..2047], B[2048..6143]
    const int b = blockIdx.y;
    const int p = blockIdx.x;
    // decode p -> (ti, sj): ti in [0,64), sj in [0, ti/2]  (64-row x 128-col tiles)
    int m0 = (int)((sqrtf(4.0f * (float)p + 1.0f) - 1.0f) * 0.5f);
    while ((m0 + 1) * (m0 + 2) <= p) m0++;
    while (m0 * (m0 + 1) > p) m0--;
    int ti = 2 * m0, base = m0 * (m0 + 1);
    if (p - base > m0) { ti++; base += m0 + 1; }
    const int sj = p - base;
    const int t0 = ti * TM, s0 = sj * TS;

    const int l = threadIdx.x;                 // 0..63: one full wave
    const int qa = l >> 4, la = l & 15;

    const unsigned short* Ab = xn + (size_t)(b * T_ + t0) * D_;
    const unsigned short* Bb = xn + (size_t)(b * T_ + s0) * D_;

    // DMA source addressing: DMA instr j covers rows [16j,16j+16); lane l ->
    // row 16j + l/4, LDS position l&3, which must hold global chunk
    // (l&3) ^ (r&3) ^ ((r>>2)&3) = (l&3)^((l>>2)&3)^((l>>4)&3)  (j-independent)
    const int ca = (l & 3) ^ ((l >> 2) & 3) ^ ((l >> 4) & 3);
    const unsigned short* gA = Ab + (size_t)(l >> 2) * D_ + ca * 8;
    const unsigned short* gB = Bb + (size_t)(l >> 2) * D_ + ca * 8;

    // reader swizzle: row i*16+la -> pos = qa ^ (la&3) ^ ((la>>2)&3)
    const int pos8 = ((qa ^ (la & 3) ^ ((la >> 2) & 3)) & 3) * 8;

#define STAGE(step, st)                                                      \
    do {                                                                     \
        _Pragma("unroll")                                                    \
        for (int j_ = 0; j_ < 4; j_++)                                       \
            async16(gA + (size_t)j_ * 16 * D_ + (step) * BK,                 \
                    &Buf[st][j_ * 512]);                                     \
        _Pragma("unroll")                                                    \
        for (int j_ = 0; j_ < 8; j_++)                                       \
            async16(gB + (size_t)j_ * 16 * D_ + (step) * BK,                 \
                    &Buf[st][2048 + j_ * 512]);                              \
    } while (0)

    f32x4 acc[4][8];
#pragma unroll
    for (int i = 0; i < 4; i++)
#pragma unroll
        for (int j = 0; j < 8; j++) acc[i][j] = (f32x4){0.f, 0.f, 0.f, 0.f};

    STAGE(0, 0);                               // prologue

#pragma unroll
    for (int k = 0; k < STEPS; ++k) {
        if (k + 1 < STEPS) {
            STAGE(k + 1, (k + 1) & 1);
            __builtin_amdgcn_s_waitcnt(0x0F7C);   // vmcnt(12): step-k's done
        } else {
            __builtin_amdgcn_s_waitcnt(0x0F70);   // vmcnt(0): last step
        }
        __asm__ __volatile__("" ::: "memory");    // pin ds_reads after waitcnt

        const unsigned short* S = &Buf[k & 1][0];
        bf16x8 af[4], bfr[8];
#pragma unroll
        for (int i = 0; i < 4; i++)
            af[i] = *(const bf16x8*)&S[(i * 16 + la) * 32 + pos8];
#pragma unroll
        for (int j = 0; j < 8; j++)
            bfr[j] = *(const bf16x8*)&S[2048 + (j * 16 + la) * 32 + pos8];
#pragma unroll
        for (int i = 0; i < 4; i++)
#pragma unroll
            for (int j = 0; j < 8; j++)
                acc[i][j] = __builtin_amdgcn_mfma_f32_16x16x32_bf16(af[i], bfr[j], acc[i][j], 0, 0, 0);
    }
#undef STAGE

    // epilogue: per-row max over this tile's s-cols (causal predicate), then
    // atomicMax. C/D layout (verified): col = lane&15, row = (lane>>4)*4+reg
#pragma unroll
    for (int i = 0; i < 4; i++) {
#pragma unroll
        for (int r = 0; r < 4; r++) {
            int tg = t0 + i * 16 + qa * 4 + r;    // global t row
            float mx = -2.0f;
#pragma unroll
            for (int j = 0; j < 8; j++) {
                int sg = s0 + j * 16 + la;        // global s col
                float v = acc[i][j][r];
                if (sg < tg) mx = fmaxf(mx, v);
            }
#pragma unroll
            for (int off = 1; off < 16; off <<= 1) mx = fmaxf(mx, __shfl_xor(mx, off));
            if (la == 0) atomicMax(&maxsim[b * T_ + tg], f2ord(mx));
        }
    }
}

// ---- Kernel 3: gate + tanh-GELU, one float4 per thread ----
__device__ __forceinline__ float gelu_tanh(float y) {
    float t = tanhf(0.7978845608028654f * (y + 0.044715f * y * y * y));
    return 0.5f * y * (1.0f + t);
}

__global__ __launch_bounds__(256) void k_gate(const float* __restrict__ x,
                                              const float* __restrict__ log_alpha,
                                              const unsigned* __restrict__ maxsim,
                                              float* __restrict__ out) {
    int idx = blockIdx.x * 256 + threadIdx.x;     // one float4 per thread
    float la = log_alpha[0];
    float alpha = (la > 20.0f) ? la : log1pf(expf(la));
    int row = idx >> 7;                           // 128 float4-threads per row
    float m = fmaxf(ord2f(maxsim[row]), -1.0f);
    float novelty = 1.0f - (m + 1.0f) * 0.5f;
    float gate = 1.0f + alpha * novelty;
    float4 v = ((const float4*)x)[idx];
    float4 o;
    o.x = gelu_tanh(v.x * gate);
    o.y = gelu_tanh(v.y * gate);
    o.z = gelu_tanh(v.z * gate);
    o.w = gelu_tanh(v.w * gate);
    ((float4*)out)[idx] = o;
}

extern "C" void kernel_launch(void* const* d_in, const int* in_sizes, int n_in,
                              void* d_out, int out_size, void* d_ws, size_t ws_size,
                              hipStream_t stream) {
    const float* x = (const float*)d_in[0];
    const float* log_alpha = (const float*)d_in[1];
    float* out = (float*)d_out;

    unsigned* maxsim = (unsigned*)d_ws;
    unsigned short* xn = (unsigned short*)((char*)d_ws + 65536);

    const int rows = B_ * T_;                     // 16384
    k_norm<<<rows / 4, 256, 0, stream>>>(x, xn, maxsim);

    dim3 g2(NPAIR, B_);
    k_maxsim<<<g2, 64, 0, stream>>>(xn, maxsim);

    k_gate<<<(B_ * T_ * D_ / 4) / 256, 256, 0, stream>>>(x, log_alpha, maxsim, out);
}

// Round 8
// 139.782 us; speedup vs baseline: 1.1410x; 1.1410x over previous
//
#include <hip/hip_runtime.h>
#include <hip/hip_bf16.h>
#include <math.h>

// Problem shape (fixed): x [B,T,D] fp32, log_alpha scalar fp32, out [B,T,D] fp32.
#define B_ 4
#define T_ 4096
#define D_ 512
#define BM 256                 // t rows per block
#define BN 128                 // s cols per block
#define BK 32                  // K per pipeline step
#define STEPS (D_ / BK)        // 16
#define NPAIR 272              // sum_{ti=0}^{15} (2*ti+2) causal (256-row x 128-col) tile pairs

// Workspace layout (needs 64 KiB + 16 MiB):
//   [0 .. 64KiB)                maxsim as order-preserving uint32 [B*T]
//   [64KiB .. 64KiB+B*T*D*2)    xn: normalized rows, bf16 bits (ushort)

typedef short bf16x8 __attribute__((ext_vector_type(8)));
typedef float f32x4 __attribute__((ext_vector_type(4)));

__device__ __forceinline__ unsigned short f2bf(float f) {
    unsigned u = __float_as_uint(f);
    u += 0x7FFFu + ((u >> 16) & 1u);   // RNE
    return (unsigned short)(u >> 16);
}
// monotone float -> uint so unsigned atomicMax orders like float
__device__ __forceinline__ unsigned f2ord(float f) {
    unsigned u = __float_as_uint(f);
    return (u & 0x80000000u) ? ~u : (u | 0x80000000u);
}
__device__ __forceinline__ float ord2f(unsigned u) {
    unsigned b = (u & 0x80000000u) ? (u ^ 0x80000000u) : ~u;
    return __uint_as_float(b);
}

__device__ __forceinline__ void async16(const unsigned short* g, unsigned short* l) {
    // 16B/lane global->LDS DMA; LDS dest = wave-uniform base + lane*16
    __builtin_amdgcn_global_load_lds(
        (const __attribute__((address_space(1))) unsigned int*)g,
        (__attribute__((address_space(3))) unsigned int*)l, 16, 0, 0);
}

// ---- Kernel 1: one wave per row. inv-norm + bf16 row write + maxsim init ----
__global__ __launch_bounds__(256) void k_norm(const float* __restrict__ x,
                                              unsigned short* __restrict__ xn,
                                              unsigned* __restrict__ maxsim) {
    int w = (blockIdx.x * 256 + threadIdx.x) >> 6;   // row id (B*T rows)
    int lane = threadIdx.x & 63;
    const float4* xr = (const float4*)(x + (size_t)w * D_);
    float4 a = xr[lane];          // lane-contiguous: full coalescing
    float4 b = xr[lane + 64];
    float ss = a.x * a.x + a.y * a.y + a.z * a.z + a.w * a.w +
               b.x * b.x + b.y * b.y + b.z * b.z + b.w * b.w;
#pragma unroll
    for (int off = 32; off > 0; off >>= 1) ss += __shfl_xor(ss, off);
    float inv = 1.0f / fmaxf(sqrtf(ss), 1e-12f);
    unsigned u0 = (unsigned)f2bf(a.x * inv) | ((unsigned)f2bf(a.y * inv) << 16);
    unsigned u1 = (unsigned)f2bf(a.z * inv) | ((unsigned)f2bf(a.w * inv) << 16);
    unsigned u2 = (unsigned)f2bf(b.x * inv) | ((unsigned)f2bf(b.y * inv) << 16);
    unsigned u3 = (unsigned)f2bf(b.z * inv) | ((unsigned)f2bf(b.w * inv) << 16);
    uint2* xo = (uint2*)(xn + (size_t)w * D_);
    xo[lane]      = make_uint2(u0, u1);
    xo[lane + 64] = make_uint2(u2, u3);
    if (lane == 0) maxsim[w] = f2ord(-2.0f);
}

// ---- Kernel 2: 256x128 block tile, 4 waves (each 64 rows x 128 cols) ----
// R6's 3-stage circular DMA pipeline (one raw s_barrier/step, fine vmcnt),
// with 2x the per-wave MFMA run (32 indep MFMAs between barriers) and
// 0.75x the LDS-read cost per FLOP. acc = 4x8 f32x4 = 128 AGPRs;
// launch_bounds(256,2) caps arch VGPRs at 128 (frags+addrs fit; acc is AGPR).
// XOR swizzle (R2-measured ZERO conflicts): LDS pos of chunk c, row r is
// (c&3)^((r>>1)&3); reader uses qa^((la>>1)&3).
// History: (256,4) spilled (R2); BK=64 killed occupancy (R3); global-direct
// frags are TA-bound (R5); 1-wave blocks have no TLP (R7).
__global__ __launch_bounds__(256, 2) void k_maxsim(const unsigned short* __restrict__ xn,
                                                   unsigned* __restrict__ maxsim) {
    // per stage: A = 8192 elems (256x32), B = 4096 elems (128x32); 3 stages
    __shared__ __align__(16) unsigned short Buf[3][12288];
    const int b = blockIdx.y;
    const int p = blockIdx.x;
    // decode p -> (ti, sj): base(ti) = ti*(ti+1), count 2*ti+2
    int ti = (int)((sqrtf(4.0f * (float)p + 1.0f) - 1.0f) * 0.5f);
    while ((ti + 1) * (ti + 2) <= p) ti++;
    while (ti * (ti + 1) > p) ti--;
    const int sj = p - ti * (ti + 1);
    const int t0 = ti * BM, s0 = sj * BN;

    const int tid = threadIdx.x;
    const int wave = tid >> 6, lane = tid & 63;   // wave = t-row group (64 rows each)
    const int qa = lane >> 4, la = lane & 15;
    const int swz = (la >> 1) & 3;                // read-side row-phase XOR

    const unsigned short* Ab = xn + (size_t)(b * T_ + t0) * D_;
    const unsigned short* Bb = xn + (size_t)(b * T_ + s0) * D_;

    // DMA source pointers (hoisted). chunk index c -> row c>>2, swizzled
    // global chunk (c&3)^(((c>>2)>>1)&3).
    // A: c = j*256+tid, j=0..3 (rows 64j..64j+63); B: c = j*256+tid, j=0..1.
    const unsigned short* gA[4];
#pragma unroll
    for (int j = 0; j < 4; j++) {
        int c = j * 256 + tid, r = c >> 2, g = (c & 3) ^ ((r >> 1) & 3);
        gA[j] = Ab + (size_t)r * D_ + g * 8;
    }
    const unsigned short* gB[2];
#pragma unroll
    for (int j = 0; j < 2; j++) {
        int c = j * 256 + tid, r = c >> 2, g = (c & 3) ^ ((r >> 1) & 3);
        gB[j] = Bb + (size_t)r * D_ + g * 8;
    }
    const int ldsA0 = (wave * 64) * 8;            // wave-uniform chunk bases (elems)

#define STAGE(step, st)                                                       \
    do {                                                                      \
        _Pragma("unroll")                                                     \
        for (int j_ = 0; j_ < 4; j_++)                                        \
            async16(gA[j_] + (step) * BK, &Buf[st][(j_ * 256) * 8 + ldsA0]);  \
        _Pragma("unroll")                                                     \
        for (int j_ = 0; j_ < 2; j_++)                                        \
            async16(gB[j_] + (step) * BK,                                     \
                    &Buf[st][8192 + (j_ * 256) * 8 + ldsA0]);                 \
    } while (0)

    f32x4 acc[4][8];
#pragma unroll
    for (int i = 0; i < 4; i++)
#pragma unroll
        for (int j = 0; j < 8; j++) acc[i][j] = (f32x4){0.f, 0.f, 0.f, 0.f};

    // prologue: steps 0 and 1 in flight (6 DMA instrs each per wave)
    STAGE(0, 0);
    STAGE(1, 1);

#pragma unroll
    for (int k = 0; k < STEPS; ++k) {
        const int cur = k % 3;
        // simm16: vmcnt lo[3:0] | expcnt(7)<<4 | lgkmcnt(15)<<8
        if (k == STEPS - 1) __builtin_amdgcn_s_waitcnt(0x0F70);  // vmcnt(0)
        else                __builtin_amdgcn_s_waitcnt(0x0F76);  // vmcnt(6)
        __builtin_amdgcn_s_barrier();
        __asm__ __volatile__("" ::: "memory");   // pin LDS reads below barrier
        if (k + 2 < STEPS) STAGE(k + 2, (k + 2) % 3);

        const unsigned short* As = &Buf[cur][0];
        const unsigned short* Bs = &Buf[cur][8192];
        bf16x8 af[4], bfr[8];
#pragma unroll
        for (int i = 0; i < 4; i++)
            af[i] = *(const bf16x8*)&As[(wave * 64 + i * 16 + la) * BK + (qa ^ swz) * 8];
#pragma unroll
        for (int j = 0; j < 8; j++)
            bfr[j] = *(const bf16x8*)&Bs[(j * 16 + la) * BK + (qa ^ swz) * 8];
#pragma unroll
        for (int i = 0; i < 4; i++)
#pragma unroll
            for (int j = 0; j < 8; j++)
                acc[i][j] = __builtin_amdgcn_mfma_f32_16x16x32_bf16(af[i], bfr[j], acc[i][j], 0, 0, 0);
    }
#undef STAGE

    // epilogue: per-row max over this tile's s-cols, then atomicMax.
    // C/D layout (verified): col = lane&15, row = (lane>>4)*4 + reg
    const bool overlap = (s0 + BN) > (t0 + wave * 64);   // tile reaches diagonal?
#pragma unroll
    for (int i = 0; i < 4; i++) {
#pragma unroll
        for (int r = 0; r < 4; r++) {
            int tg = t0 + wave * 64 + i * 16 + qa * 4 + r;   // global t row
            float mx = -2.0f;
#pragma unroll
            for (int j = 0; j < 8; j++) {
                int sg = s0 + j * 16 + la;                   // global s col
                float v = acc[i][j][r];
                if (!overlap || sg < tg) mx = fmaxf(mx, v);
            }
#pragma unroll
            for (int off = 1; off < 16; off <<= 1) mx = fmaxf(mx, __shfl_xor(mx, off));
            if (la == 0) atomicMax(&maxsim[b * T_ + tg], f2ord(mx));
        }
    }
}

// ---- Kernel 3: gate + tanh-GELU, one float4 per thread ----
__device__ __forceinline__ float gelu_tanh(float y) {
    float t = tanhf(0.7978845608028654f * (y + 0.044715f * y * y * y));
    return 0.5f * y * (1.0f + t);
}

__global__ __launch_bounds__(256) void k_gate(const float* __restrict__ x,
                                              const float* __restrict__ log_alpha,
                                              const unsigned* __restrict__ maxsim,
                                              float* __restrict__ out) {
    int idx = blockIdx.x * 256 + threadIdx.x;     // one float4 per thread
    float la = log_alpha[0];
    float alpha = (la > 20.0f) ? la : log1pf(expf(la));
    int row = idx >> 7;                           // 128 float4-threads per row
    float m = fmaxf(ord2f(maxsim[row]), -1.0f);
    float novelty = 1.0f - (m + 1.0f) * 0.5f;
    float gate = 1.0f + alpha * novelty;
    float4 v = ((const float4*)x)[idx];
    float4 o;
    o.x = gelu_tanh(v.x * gate);
    o.y = gelu_tanh(v.y * gate);
    o.z = gelu_tanh(v.z * gate);
    o.w = gelu_tanh(v.w * gate);
    ((float4*)out)[idx] = o;
}

extern "C" void kernel_launch(void* const* d_in, const int* in_sizes, int n_in,
                              void* d_out, int out_size, void* d_ws, size_t ws_size,
                              hipStream_t stream) {
    const float* x = (const float*)d_in[0];
    const float* log_alpha = (const float*)d_in[1];
    float* out = (float*)d_out;

    unsigned* maxsim = (unsigned*)d_ws;
    unsigned short* xn = (unsigned short*)((char*)d_ws + 65536);

    const int rows = B_ * T_;                     // 16384
    k_norm<<<rows / 4, 256, 0, stream>>>(x, xn, maxsim);

    dim3 g2(NPAIR, B_);
    k_maxsim<<<g2, 256, 0, stream>>>(xn, maxsim);

    k_gate<<<(B_ * T_ * D_ / 4) / 256, 256, 0, stream>>>(x, log_alpha, maxsim, out);
}

// Round 9
// 133.623 us; speedup vs baseline: 1.1936x; 1.0461x over previous
//
#include <hip/hip_runtime.h>
#include <hip/hip_bf16.h>
#include <math.h>

// Problem shape (fixed): x [B,T,D] fp32, log_alpha scalar fp32, out [B,T,D] fp32.
#define B_ 4
#define T_ 4096
#define D_ 512
#define BT 128                 // t/s tile size per block (128x128 pair)
#define BK 64                  // K elems per pipeline step (fp8: 64 B/row)
#define STEPS (D_ / BK)        // 8
#define NT (T_ / BT)           // 32 tiles per batch
#define NPAIR (NT * (NT + 1) / 2)  // 528 lower-triangle tile pairs

// Workspace layout:
//   [0 .. 64KiB)                maxsim as order-preserving uint32 [B*T]
//   [64KiB .. 64KiB+B*T*D)      xn: normalized rows, fp8 e4m3 (1 B/elem, 8 MB)

typedef float f32x4 __attribute__((ext_vector_type(4)));

// monotone float -> uint so unsigned atomicMax orders like float
__device__ __forceinline__ unsigned f2ord(float f) {
    unsigned u = __float_as_uint(f);
    return (u & 0x80000000u) ? ~u : (u | 0x80000000u);
}
__device__ __forceinline__ float ord2f(unsigned u) {
    unsigned b = (u & 0x80000000u) ? (u ^ 0x80000000u) : ~u;
    return __uint_as_float(b);
}

__device__ __forceinline__ void async16(const unsigned char* g, unsigned char* l) {
    // 16B/lane global->LDS DMA; LDS dest = wave-uniform base + lane*16
    __builtin_amdgcn_global_load_lds(
        (const __attribute__((address_space(1))) unsigned int*)g,
        (__attribute__((address_space(3))) unsigned int*)l, 16, 0, 0);
}

// ---- Kernel 1: one wave per row. inv-norm + fp8 row write + maxsim init ----
__global__ __launch_bounds__(256) void k_norm(const float* __restrict__ x,
                                              unsigned char* __restrict__ xn,
                                              unsigned* __restrict__ maxsim) {
    int w = (blockIdx.x * 256 + threadIdx.x) >> 6;   // row id (B*T rows)
    int lane = threadIdx.x & 63;
    const float4* xr = (const float4*)(x + (size_t)w * D_);
    float4 a = xr[lane];          // lane-contiguous: full coalescing
    float4 b = xr[lane + 64];
    float ss = a.x * a.x + a.y * a.y + a.z * a.z + a.w * a.w +
               b.x * b.x + b.y * b.y + b.z * b.z + b.w * b.w;
#pragma unroll
    for (int off = 32; off > 0; off >>= 1) ss += __shfl_xor(ss, off);
    float inv = 1.0f / fmaxf(sqrtf(ss), 1e-12f);
    // pack 8 floats -> 8 fp8 e4m3 (OCP on gfx950) via v_cvt_pk_fp8_f32
    int u0 = __builtin_amdgcn_cvt_pk_fp8_f32(a.x * inv, a.y * inv, 0, false);
    u0 = __builtin_amdgcn_cvt_pk_fp8_f32(a.z * inv, a.w * inv, u0, true);
    int u1 = __builtin_amdgcn_cvt_pk_fp8_f32(b.x * inv, b.y * inv, 0, false);
    u1 = __builtin_amdgcn_cvt_pk_fp8_f32(b.z * inv, b.w * inv, u1, true);
    unsigned* xo = (unsigned*)(xn + (size_t)w * D_);
    xo[lane]      = (unsigned)u0;   // elems 4*lane .. 4*lane+3
    xo[lane + 64] = (unsigned)u1;   // elems 256+4*lane ..
    if (lane == 0) maxsim[w] = f2ord(-2.0f);
}

// ---- Kernel 2: one block per (ti,si) pair; fp8 MFMA; R6 3-stage pipeline ----
// Structure (R6-proven): 3-stage circular DMA buffer, ONE raw s_barrier per
// K-step, in-loop wait vmcnt(4) (step-k's 4 DMAs, issued 2 steps ago; k+1's
// stay in flight). fp8 halves all LDS bytes; BK=64 halves the barrier count
// (8 steps) at the SAME 16 KB/stage LDS footprint as bf16-BK=32.
// LDS per stage: A[128 rows][64 B] then B at +8192. Chunk-XOR swizzle:
// 16B chunk at position p of row r holds global chunk p ^ ((r>>1)&3)
// (R2-verified family). Fragment reads are b64 (8 B/lane).
// History: (256,4) spilled (R2); bf16-BK=64 killed occupancy (R3, 32KB/stage);
// global-direct frags TA-bound (R5); 1-wave blocks no TLP (R7); 256x128
// tile lost to occupancy+tail (R8).
__global__ __launch_bounds__(256) void k_maxsim(const unsigned char* __restrict__ xn,
                                                unsigned* __restrict__ maxsim) {
    __shared__ __align__(16) unsigned char Buf[3][16384];
    const int b = blockIdx.y;
    const int p = blockIdx.x;
    // triangular decode p -> (ti, si), si <= ti
    int ti = (int)((sqrtf(8.0f * (float)p + 1.0f) - 1.0f) * 0.5f);
    while ((ti + 1) * (ti + 2) / 2 <= p) ti++;
    while (ti * (ti + 1) / 2 > p) ti--;
    const int si = p - ti * (ti + 1) / 2;
    const int t0 = ti * BT, s0 = si * BT;

    const int tid = threadIdx.x;
    const int wave = tid >> 6, lane = tid & 63;
    const int wm = wave >> 1, wn = wave & 1;     // 2x2 waves -> 64x64 each
    const int qa = lane >> 4, la = lane & 15;
    const int swz = (la >> 1) & 3;               // read-side row-phase XOR

    const unsigned char* Ab = xn + (size_t)(b * T_ + t0) * D_;
    const unsigned char* Bb = xn + (size_t)(b * T_ + s0) * D_;

    // DMA addressing: chunk index c -> row r = c>>2 (4x16B chunks = 64 B/row),
    // position p = c&3, global chunk g = p ^ ((r>>1)&3).
    // A: instrs j=0,1 (c = j*256+tid); B: same with own base.
    const int c0 = tid,       r0_ = c0 >> 2, g0 = (c0 & 3) ^ ((r0_ >> 1) & 3);
    const int c1 = 256 + tid, r1_ = c1 >> 2, g1 = (c1 & 3) ^ ((r1_ >> 1) & 3);
    const unsigned char* gA0 = Ab + (size_t)r0_ * D_ + g0 * 16;
    const unsigned char* gA1 = Ab + (size_t)r1_ * D_ + g1 * 16;
    const unsigned char* gB0 = Bb + (size_t)r0_ * D_ + g0 * 16;
    const unsigned char* gB1 = Bb + (size_t)r1_ * D_ + g1 * 16;
    const int ldsb0 = (wave * 64) * 16;          // wave-uniform chunk base (bytes)
    const int ldsb1 = (256 + wave * 64) * 16;

#define STAGE(step, st)                                            \
    do {                                                           \
        async16(gA0 + (step) * BK, &Buf[st][ldsb0]);               \
        async16(gB0 + (step) * BK, &Buf[st][8192 + ldsb0]);        \
        async16(gA1 + (step) * BK, &Buf[st][ldsb1]);               \
        async16(gB1 + (step) * BK, &Buf[st][8192 + ldsb1]);        \
    } while (0)

    f32x4 acc[4][4];
#pragma unroll
    for (int i = 0; i < 4; i++)
#pragma unroll
        for (int j = 0; j < 4; j++) acc[i][j] = (f32x4){0.f, 0.f, 0.f, 0.f};

    // reader byte offsets within a 64-B row slab for MFMA k-half h:
    // global 8B unit = h*2 + (qa>>1) chunk, (qa&1)*8 within chunk; swizzled.
    const int poff0 = (((qa >> 1) ^ swz) * 16) + (qa & 1) * 8;
    const int poff1 = ((((qa >> 1) + 2) ^ swz) * 16) + (qa & 1) * 8;

    // prologue: steps 0 and 1 in flight (4 DMA instrs each per wave)
    STAGE(0, 0);
    STAGE(1, 1);

#pragma unroll
    for (int k = 0; k < STEPS; ++k) {
        const int cur = k % 3;
        // simm16: vmcnt lo[3:0] | expcnt(7)<<4 | lgkmcnt(15)<<8
        if (k == STEPS - 1) __builtin_amdgcn_s_waitcnt(0x0F70);  // vmcnt(0)
        else                __builtin_amdgcn_s_waitcnt(0x0F74);  // vmcnt(4)
        __builtin_amdgcn_s_barrier();
        __asm__ __volatile__("" ::: "memory");   // pin LDS reads below barrier
        if (k + 2 < STEPS) STAGE(k + 2, (k + 2) % 3);

        const unsigned char* As = &Buf[cur][0];
        const unsigned char* Bs = &Buf[cur][8192];
#pragma unroll
        for (int h = 0; h < 2; h++) {            // two MFMA k-halves of 32
            const int poff = h ? poff1 : poff0;
            long af[4], bfr[4];
#pragma unroll
            for (int i = 0; i < 4; i++)
                af[i] = *(const long*)&As[(wm * 64 + i * 16 + la) * 64 + poff];
#pragma unroll
            for (int j = 0; j < 4; j++)
                bfr[j] = *(const long*)&Bs[(wn * 64 + j * 16 + la) * 64 + poff];
#pragma unroll
            for (int i = 0; i < 4; i++)
#pragma unroll
                for (int j = 0; j < 4; j++)
                    acc[i][j] = __builtin_amdgcn_mfma_f32_16x16x32_fp8_fp8(
                        af[i], bfr[j], acc[i][j], 0, 0, 0);
        }
    }
#undef STAGE

    // epilogue: per-row max over this tile's s-columns, then global atomicMax.
    // C/D layout (verified, dtype-independent): col = lane&15, row = (lane>>4)*4+reg
    const bool diag = (ti == si);
#pragma unroll
    for (int i = 0; i < 4; i++) {
#pragma unroll
        for (int r = 0; r < 4; r++) {
            int tl = wm * 64 + i * 16 + qa * 4 + r;   // local t row
            float m = -2.0f;
#pragma unroll
            for (int j = 0; j < 4; j++) {
                int sl = wn * 64 + j * 16 + la;       // local s col
                float v = acc[i][j][r];
                if (!diag || sl < tl) m = fmaxf(m, v);
            }
#pragma unroll
            for (int off = 1; off < 16; off <<= 1) m = fmaxf(m, __shfl_xor(m, off));
            if (la == 0) atomicMax(&maxsim[b * T_ + t0 + tl], f2ord(m));
        }
    }
}

// ---- Kernel 3: gate + tanh-GELU, one float4 per thread ----
__device__ __forceinline__ float gelu_tanh(float y) {
    float t = tanhf(0.7978845608028654f * (y + 0.044715f * y * y * y));
    return 0.5f * y * (1.0f + t);
}

__global__ __launch_bounds__(256) void k_gate(const float* __restrict__ x,
                                              const float* __restrict__ log_alpha,
                                              const unsigned* __restrict__ maxsim,
                                              float* __restrict__ out) {
    int idx = blockIdx.x * 256 + threadIdx.x;     // one float4 per thread
    float la = log_alpha[0];
    float alpha = (la > 20.0f) ? la : log1pf(expf(la));
    int row = idx >> 7;                           // 128 float4-threads per row
    float m = fmaxf(ord2f(maxsim[row]), -1.0f);
    float novelty = 1.0f - (m + 1.0f) * 0.5f;
    float gate = 1.0f + alpha * novelty;
    float4 v = ((const float4*)x)[idx];
    float4 o;
    o.x = gelu_tanh(v.x * gate);
    o.y = gelu_tanh(v.y * gate);
    o.z = gelu_tanh(v.z * gate);
    o.w = gelu_tanh(v.w * gate);
    ((float4*)out)[idx] = o;
}

extern "C" void kernel_launch(void* const* d_in, const int* in_sizes, int n_in,
                              void* d_out, int out_size, void* d_ws, size_t ws_size,
                              hipStream_t stream) {
    const float* x = (const float*)d_in[0];
    const float* log_alpha = (const float*)d_in[1];
    float* out = (float*)d_out;

    unsigned* maxsim = (unsigned*)d_ws;
    unsigned char* xn = (unsigned char*)d_ws + 65536;

    const int rows = B_ * T_;                     // 16384
    k_norm<<<rows / 4, 256, 0, stream>>>(x, xn, maxsim);

    dim3 g2(NPAIR, B_);
    k_maxsim<<<g2, 256, 0, stream>>>(xn, maxsim);

    k_gate<<<(B_ * T_ * D_ / 4) / 256, 256, 0, stream>>>(x, log_alpha, maxsim, out);
}

// Round 10
// 129.726 us; speedup vs baseline: 1.2294x; 1.0300x over previous
//
#include <hip/hip_runtime.h>
#include <hip/hip_bf16.h>
#include <math.h>

// Problem shape (fixed): x [B,T,D] fp32, log_alpha scalar fp32, out [B,T,D] fp32.
#define B_ 4
#define T_ 4096
#define D_ 512
#define BT 128                 // t/s tile size per block (128x128 pair)
#define BK 64                  // K elems per pipeline step (fp8: 64 B/row)
#define STEPS (D_ / BK)        // 8
#define NT (T_ / BT)           // 32 tiles per batch
#define NPAIR (NT * (NT + 1) / 2)  // 528 lower-triangle tile pairs

// Workspace layout:
//   [0 .. 64KiB)                maxsim as order-preserving uint32 [B*T]
//   [64KiB .. 64KiB+B*T*D)      xn: normalized rows, fp8 e4m3, UNIT-INTERLEAVED:
//     within each 64-elem K-slab, 16B chunk C holds logical 8B units
//     {elems C*8..C*8+7} (h=0) then {elems 32+C*8..+7} (h=1). This makes one
//     ds_read_b128 serve both MFMA k-halves of a row -> R2's verified
//     zero-conflict LDS read pattern (vs R9's 4-way-conflicted b64 reads).

typedef float f32x4 __attribute__((ext_vector_type(4)));
typedef long i64x2 __attribute__((ext_vector_type(2)));

// monotone float -> uint so unsigned atomicMax orders like float
__device__ __forceinline__ unsigned f2ord(float f) {
    unsigned u = __float_as_uint(f);
    return (u & 0x80000000u) ? ~u : (u | 0x80000000u);
}
__device__ __forceinline__ float ord2f(unsigned u) {
    unsigned b = (u & 0x80000000u) ? (u ^ 0x80000000u) : ~u;
    return __uint_as_float(b);
}

__device__ __forceinline__ void async16(const unsigned char* g, unsigned char* l) {
    // 16B/lane global->LDS DMA; LDS dest = wave-uniform base + lane*16
    __builtin_amdgcn_global_load_lds(
        (const __attribute__((address_space(1))) unsigned int*)g,
        (__attribute__((address_space(3))) unsigned int*)l, 16, 0, 0);
}

// ---- Kernel 1: one wave per row. inv-norm + permuted fp8 write + init ----
__global__ __launch_bounds__(256) void k_norm(const float* __restrict__ x,
                                              unsigned char* __restrict__ xn,
                                              unsigned* __restrict__ maxsim) {
    int w = (blockIdx.x * 256 + threadIdx.x) >> 6;   // row id (B*T rows)
    int l = threadIdx.x & 63;
    const float4* xr = (const float4*)(x + (size_t)w * D_);
    float4 a = xr[l];             // elems 4l..4l+3
    float4 b = xr[l + 64];        // elems 256+4l..
    float ss = a.x * a.x + a.y * a.y + a.z * a.z + a.w * a.w +
               b.x * b.x + b.y * b.y + b.z * b.z + b.w * b.w;
#pragma unroll
    for (int off = 32; off > 0; off >>= 1) ss += __shfl_xor(ss, off);
    float inv = 1.0f / fmaxf(sqrtf(ss), 1e-12f);
    int u0 = __builtin_amdgcn_cvt_pk_fp8_f32(a.x * inv, a.y * inv, 0, false);
    u0 = __builtin_amdgcn_cvt_pk_fp8_f32(a.z * inv, a.w * inv, u0, true);
    int u1 = __builtin_amdgcn_cvt_pk_fp8_f32(b.x * inv, b.y * inv, 0, false);
    u1 = __builtin_amdgcn_cvt_pk_fp8_f32(b.z * inv, b.w * inv, u1, true);
    // permuted address (in uints) for elem group e0=4l:
    //   slab (l>>4)*16 | chunk ((l>>1)&3)*4 | half ((l>>3)&1)*2 | (l&1)
    unsigned* xo = (unsigned*)(xn + (size_t)w * D_);
    int off4 = (l >> 4) * 16 + ((l >> 1) & 3) * 4 + ((l >> 3) & 1) * 2 + (l & 1);
    xo[off4]      = (unsigned)u0;   // elems 4l..4l+3
    xo[off4 + 64] = (unsigned)u1;   // elems 256+4l.. (+4 slabs = +256 B)
    if (l == 0) maxsim[w] = f2ord(-2.0f);
}

// ---- Kernel 2: one block per (ti,si) pair; fp8 MFMA; R6 3-stage pipeline ----
// 3-stage circular DMA buffer, ONE raw s_barrier per K-step, in-loop wait
// vmcnt(4). BK=64 fp8: 16 KB/stage (same as R6 bf16), 8 steps, 32 MFMA/step.
// LDS per stage: A[128 rows][64 B] then B at +8192. Chunk-XOR swizzle
// (R2-verified ZERO conflicts): 16B chunk at position P of row r holds
// global chunk P ^ ((r>>1)&3); reader b128 at position qa^((la>>1)&3) gets
// both k-half fragments (unit-interleaved xn layout).
// History: (256,4) spilled (R2); bf16-BK=64 killed occupancy (R3); global-
// direct frags TA-bound (R5); 1-wave blocks no TLP (R7); 256x128 tile lost
// to occupancy+tail (R8); b64 frag reads 4-way conflicted (R9).
__global__ __launch_bounds__(256) void k_maxsim(const unsigned char* __restrict__ xn,
                                                unsigned* __restrict__ maxsim) {
    __shared__ __align__(16) unsigned char Buf[3][16384];
    const int b = blockIdx.y;
    const int p = blockIdx.x;
    // triangular decode p -> (ti, si), si <= ti
    int ti = (int)((sqrtf(8.0f * (float)p + 1.0f) - 1.0f) * 0.5f);
    while ((ti + 1) * (ti + 2) / 2 <= p) ti++;
    while (ti * (ti + 1) / 2 > p) ti--;
    const int si = p - ti * (ti + 1) / 2;
    const int t0 = ti * BT, s0 = si * BT;

    const int tid = threadIdx.x;
    const int wave = tid >> 6, lane = tid & 63;
    const int wm = wave >> 1, wn = wave & 1;     // 2x2 waves -> 64x64 each
    const int qa = lane >> 4, la = lane & 15;
    const int swz = (la >> 1) & 3;               // read-side row-phase XOR

    const unsigned char* Ab = xn + (size_t)(b * T_ + t0) * D_;
    const unsigned char* Bb = xn + (size_t)(b * T_ + s0) * D_;

    // DMA addressing: chunk index c -> row r = c>>2 (4x16B chunks = 64 B/row),
    // position c&3 holds global chunk g = (c&3) ^ ((r>>1)&3).
    const int c0 = tid,       r0_ = c0 >> 2, g0 = (c0 & 3) ^ ((r0_ >> 1) & 3);
    const int c1 = 256 + tid, r1_ = c1 >> 2, g1 = (c1 & 3) ^ ((r1_ >> 1) & 3);
    const unsigned char* gA0 = Ab + (size_t)r0_ * D_ + g0 * 16;
    const unsigned char* gA1 = Ab + (size_t)r1_ * D_ + g1 * 16;
    const unsigned char* gB0 = Bb + (size_t)r0_ * D_ + g0 * 16;
    const unsigned char* gB1 = Bb + (size_t)r1_ * D_ + g1 * 16;
    const int ldsb0 = (wave * 64) * 16;          // wave-uniform chunk base (bytes)
    const int ldsb1 = (256 + wave * 64) * 16;

#define STAGE(step, st)                                            \
    do {                                                           \
        async16(gA0 + (step) * BK, &Buf[st][ldsb0]);               \
        async16(gB0 + (step) * BK, &Buf[st][8192 + ldsb0]);        \
        async16(gA1 + (step) * BK, &Buf[st][ldsb1]);               \
        async16(gB1 + (step) * BK, &Buf[st][8192 + ldsb1]);        \
    } while (0)

    f32x4 acc[4][4];
#pragma unroll
    for (int i = 0; i < 4; i++)
#pragma unroll
        for (int j = 0; j < 4; j++) acc[i][j] = (f32x4){0.f, 0.f, 0.f, 0.f};

    const int rpos = (qa ^ swz) * 16;            // b128 position within 64-B row

    // prologue: steps 0 and 1 in flight (4 DMA instrs each per wave)
    STAGE(0, 0);
    STAGE(1, 1);

#pragma unroll
    for (int k = 0; k < STEPS; ++k) {
        const int cur = k % 3;
        // simm16: vmcnt lo[3:0] | expcnt(7)<<4 | lgkmcnt(15)<<8
        if (k == STEPS - 1) __builtin_amdgcn_s_waitcnt(0x0F70);  // vmcnt(0)
        else                __builtin_amdgcn_s_waitcnt(0x0F74);  // vmcnt(4)
        __builtin_amdgcn_s_barrier();
        __asm__ __volatile__("" ::: "memory");   // pin LDS reads below barrier
        if (k + 2 < STEPS) STAGE(k + 2, (k + 2) % 3);

        const unsigned char* As = &Buf[cur][0];
        const unsigned char* Bs = &Buf[cur][8192];
        // ONE b128 per row: [0]=h0 fragment (k 0..31), [1]=h1 (k 32..63)
        i64x2 af[4], bfr[4];
#pragma unroll
        for (int i = 0; i < 4; i++)
            af[i] = *(const i64x2*)&As[(wm * 64 + i * 16 + la) * 64 + rpos];
#pragma unroll
        for (int j = 0; j < 4; j++)
            bfr[j] = *(const i64x2*)&Bs[(wn * 64 + j * 16 + la) * 64 + rpos];
#pragma unroll
        for (int h = 0; h < 2; h++)
#pragma unroll
            for (int i = 0; i < 4; i++)
#pragma unroll
                for (int j = 0; j < 4; j++)
                    acc[i][j] = __builtin_amdgcn_mfma_f32_16x16x32_fp8_fp8(
                        af[i][h], bfr[j][h], acc[i][j], 0, 0, 0);
    }
#undef STAGE

    // epilogue: per-row max over this tile's s-columns, then global atomicMax.
    // C/D layout (verified, dtype-independent): col = lane&15, row = (lane>>4)*4+reg
    const bool diag = (ti == si);
#pragma unroll
    for (int i = 0; i < 4; i++) {
#pragma unroll
        for (int r = 0; r < 4; r++) {
            int tl = wm * 64 + i * 16 + qa * 4 + r;   // local t row
            float m = -2.0f;
#pragma unroll
            for (int j = 0; j < 4; j++) {
                int sl = wn * 64 + j * 16 + la;       // local s col
                float v = acc[i][j][r];
                if (!diag || sl < tl) m = fmaxf(m, v);
            }
#pragma unroll
            for (int off = 1; off < 16; off <<= 1) m = fmaxf(m, __shfl_xor(m, off));
            if (la == 0) atomicMax(&maxsim[b * T_ + t0 + tl], f2ord(m));
        }
    }
}

// ---- Kernel 3: gate + tanh-GELU, one float4 per thread ----
__device__ __forceinline__ float gelu_tanh(float y) {
    float t = tanhf(0.7978845608028654f * (y + 0.044715f * y * y * y));
    return 0.5f * y * (1.0f + t);
}

__global__ __launch_bounds__(256) void k_gate(const float* __restrict__ x,
                                              const float* __restrict__ log_alpha,
                                              const unsigned* __restrict__ maxsim,
                                              float* __restrict__ out) {
    int idx = blockIdx.x * 256 + threadIdx.x;     // one float4 per thread
    float la = log_alpha[0];
    float alpha = (la > 20.0f) ? la : log1pf(expf(la));
    int row = idx >> 7;                           // 128 float4-threads per row
    float m = fmaxf(ord2f(maxsim[row]), -1.0f);
    float novelty = 1.0f - (m + 1.0f) * 0.5f;
    float gate = 1.0f + alpha * novelty;
    float4 v = ((const float4*)x)[idx];
    float4 o;
    o.x = gelu_tanh(v.x * gate);
    o.y = gelu_tanh(v.y * gate);
    o.z = gelu_tanh(v.z * gate);
    o.w = gelu_tanh(v.w * gate);
    ((float4*)out)[idx] = o;
}

extern "C" void kernel_launch(void* const* d_in, const int* in_sizes, int n_in,
                              void* d_out, int out_size, void* d_ws, size_t ws_size,
                              hipStream_t stream) {
    const float* x = (const float*)d_in[0];
    const float* log_alpha = (const float*)d_in[1];
    float* out = (float*)d_out;

    unsigned* maxsim = (unsigned*)d_ws;
    unsigned char* xn = (unsigned char*)d_ws + 65536;

    const int rows = B_ * T_;                     // 16384
    k_norm<<<rows / 4, 256, 0, stream>>>(x, xn, maxsim);

    dim3 g2(NPAIR, B_);
    k_maxsim<<<g2, 256, 0, stream>>>(xn, maxsim);

    k_gate<<<(B_ * T_ * D_ / 4) / 256, 256, 0, stream>>>(x, log_alpha, maxsim, out);
}